// Round 6
// baseline (87.178 us; speedup 1.0000x reference)
//
#include <hip/hip_runtime.h>

// QuantumKernelMethod: analytic collapse.
//   out[x,y] = M^2,  M = prod_i cos((x_i - y_i)/2)
//            = prod_i [cos(x_i/2)cos(y_i/2) + sin(x_i/2)sin(y_i/2)]
// (params provably unused: the RZ phases / CNOT permutation are sample-
// independent and cancel in |<psi_x|psi_y>|^2.)
//
// Ladder: R1 two-kernel 100.8us -> R3 fused 89.4 -> R5 tan-factored+packed
// 83.0. R6: CPT=4 (one b128 store/row, half the LDS record reads per elem)
// + nontemporal stores. NO min-waves launch bound (R2 lesson: the 128-VGPR
// cap, not CPT=4, caused the 374 MB spill storm).
// Math per row per thread: p = Cx * prod_w (cy_w + tx_w * sy_w), out = p^2,
// with tx/Cx per-row in LDS (broadcast reads), y (cos,sin) in packed regs.

#define NS 4096   // samples per set
#define NW 10     // wires
#define ROWS 32   // rows per block
#define CPT 4     // columns per thread (two packed pairs, one b128 store)

typedef float v2f __attribute__((ext_vector_type(2)));
typedef float v4f __attribute__((ext_vector_type(4)));

static __device__ inline v2f splat2(float x) { v2f v; v.x = x; v.y = x; return v; }

__global__ __launch_bounds__(256) void qkm_fused(
    const float* __restrict__ X, const float* __restrict__ Y,
    float* __restrict__ out) {
    __shared__ float xrow[ROWS][12];   // per row: tx[0..9], Cx, pad (48 B)
    __shared__ float cxa[ROWS][NW];    // staging for the Cx product reduce

    const int col  = (blockIdx.x * 256 + threadIdx.x) * CPT;
    const int row0 = blockIdx.y * ROWS;

    // Stage per-(row,wire): tan(x/2) and cos(x/2). ROWS*NW=320 > 256 threads
    // => strided loop (R4 bug: plain `if` left rows 25..31 unstaged).
    for (int t = threadIdx.x; t < ROWS * NW; t += 256) {
        int r = t / NW;
        int w = t - r * NW;
        float s, c;
        __sincosf(0.5f * X[(row0 + r) * NW + w], &s, &c);
        // |cos(x/2)| >= ~4e-8 for representable x in [0,2pi]; guard anyway.
        float cs = (fabsf(c) < 1e-30f) ? copysignf(1e-30f, c) : c;
        xrow[r][w] = __fdividef(s, cs);   // tx = tan(x/2)
        cxa[r][w]  = cs;
    }

    // This thread's 4 columns: (cos,sin) of Y half-angles, two packed pairs.
    v2f cy[NW][2], sy[NW][2];
#pragma unroll
    for (int j = 0; j < 2; ++j) {
#pragma unroll
        for (int w = 0; w < NW; ++w) {
            float s0, c0, s1, c1;
            __sincosf(0.5f * Y[(size_t)(col + 2 * j) * NW + w], &s0, &c0);
            __sincosf(0.5f * Y[(size_t)(col + 2 * j + 1) * NW + w], &s1, &c1);
            v2f c; c.x = c0; c.y = c1;
            v2f s; s.x = s0; s.y = s1;
            cy[w][j] = c; sy[w][j] = s;
        }
    }

    __syncthreads();
    if (threadIdx.x < ROWS) {                 // Cx = prod_i cos(x_i/2)
        int r = threadIdx.x;
        float p = cxa[r][0];
#pragma unroll
        for (int w = 1; w < NW; ++w) p *= cxa[r][w];
        xrow[r][NW] = p;
    }
    __syncthreads();

#pragma unroll 2
    for (int r = 0; r < ROWS; ++r) {
        float a[12];                          // tx[0..9], Cx  (3x ds_read_b128)
        *reinterpret_cast<float4*>(&a[0]) = *reinterpret_cast<const float4*>(&xrow[r][0]);
        *reinterpret_cast<float4*>(&a[4]) = *reinterpret_cast<const float4*>(&xrow[r][4]);
        *reinterpret_cast<float4*>(&a[8]) = *reinterpret_cast<const float4*>(&xrow[r][8]);
        v2f p0 = splat2(a[NW]);               // start from Cx
        v2f p1 = p0;
#pragma unroll
        for (int w = 0; w < NW; ++w) {
            const v2f t = splat2(a[w]);
            p0 = p0 * (cy[w][0] + t * sy[w][0]);   // v_pk_fma + v_pk_mul
            p1 = p1 * (cy[w][1] + t * sy[w][1]);
        }
        v4f o;
        o.x = p0.x * p0.x; o.y = p0.y * p0.y;
        o.z = p1.x * p1.x; o.w = p1.y * p1.y;
        __builtin_nontemporal_store(
            o, reinterpret_cast<v4f*>(out + (size_t)(row0 + r) * NS + col));
    }
}

extern "C" void kernel_launch(void* const* d_in, const int* in_sizes, int n_in,
                              void* d_out, int out_size, void* d_ws, size_t ws_size,
                              hipStream_t stream) {
    const float* X = (const float*)d_in[0];   // (4096, 10)
    const float* Y = (const float*)d_in[1];   // (4096, 10)
    // d_in[2] = params (4,10): unused (phases cancel in |<x|y>|^2).
    float* out = (float*)d_out;               // (4096, 4096) fp32

    dim3 grid(NS / (256 * CPT), NS / ROWS);   // (4, 128)
    qkm_fused<<<grid, 256, 0, stream>>>(X, Y, out);
}